// Round 1
// baseline (3757.089 us; speedup 1.0000x reference)
//
#include <hip/hip_runtime.h>

#define D_DIM 512

// ---------------- CSR build ----------------

__global__ __launch_bounds__(256) void k_hist(const int* __restrict__ row, int* __restrict__ cnt, int E) {
  int i = blockIdx.x * blockDim.x + threadIdx.x;
  int stride = gridDim.x * blockDim.x;
  for (; i < E; i += stride) atomicAdd(&cnt[row[i]], 1);
}

__global__ __launch_bounds__(1024) void k_scan(const int* __restrict__ cnt, int* __restrict__ rp, int n) {
  __shared__ int s[1024];
  int running = 0;
  const int tid = threadIdx.x;
  for (int base = 0; base < n; base += 1024) {
    int i = base + tid;
    int v = (i < n) ? cnt[i] : 0;
    s[tid] = v;
    __syncthreads();
    for (int off = 1; off < 1024; off <<= 1) {
      int t = (tid >= off) ? s[tid - off] : 0;
      __syncthreads();
      s[tid] += t;
      __syncthreads();
    }
    if (i < n) rp[i] = running + s[tid] - v;  // exclusive
    int tot = s[1023];
    __syncthreads();
    running += tot;
  }
  if (tid == 0) rp[n] = running;
}

__global__ __launch_bounds__(256) void k_scatter(const int* __restrict__ row, const int* __restrict__ col,
                                                 const float* __restrict__ val, int* __restrict__ cur,
                                                 int* __restrict__ scol, float* __restrict__ sval, int E) {
  int i = blockIdx.x * blockDim.x + threadIdx.x;
  int stride = gridDim.x * blockDim.x;
  for (; i < E; i += stride) {
    int r = row[i];
    int p = atomicAdd(&cur[r], 1);
    scol[p] = col[i];
    sval[p] = val[i];
  }
}

// ---------------- f32 GEMM: C[M,512] = A[M,512] @ B[512,512] ----------------
// 64x64 tile, BK=16, 256 threads, 4x4 microtile per thread.

__global__ __launch_bounds__(256) void k_gemm512(const float* __restrict__ A, const float* __restrict__ B,
                                                 float* __restrict__ C, int M) {
  __shared__ float As[16][64];
  __shared__ float Bs[16][64];
  const int tid = threadIdx.x;
  const int m0 = blockIdx.x * 64;
  const int n0 = blockIdx.y * 64;
  const int tm = tid >> 4, tn = tid & 15;
  const int am = tid >> 2, ak = (tid & 3) << 2;   // A tile: 64 rows x 16 k, float4 along k
  const int bk = tid >> 4, bn = (tid & 15) << 2;  // B tile: 16 k x 64 cols, float4 along col
  const int arow = m0 + am;
  float acc[4][4] = {};
  for (int k0 = 0; k0 < 512; k0 += 16) {
    float4 av = make_float4(0.f, 0.f, 0.f, 0.f);
    if (arow < M) av = *(const float4*)&A[(size_t)arow * D_DIM + k0 + ak];
    float4 bv = *(const float4*)&B[(size_t)(k0 + bk) * D_DIM + n0 + bn];
    As[ak + 0][am] = av.x;
    As[ak + 1][am] = av.y;
    As[ak + 2][am] = av.z;
    As[ak + 3][am] = av.w;
    *(float4*)&Bs[bk][bn] = bv;
    __syncthreads();
#pragma unroll
    for (int kk = 0; kk < 16; ++kk) {
      float4 a4 = *(const float4*)&As[kk][tm << 2];
      float4 b4 = *(const float4*)&Bs[kk][tn << 2];
      float av_[4] = {a4.x, a4.y, a4.z, a4.w};
      float bv_[4] = {b4.x, b4.y, b4.z, b4.w};
#pragma unroll
      for (int i = 0; i < 4; ++i)
#pragma unroll
        for (int j = 0; j < 4; ++j) acc[i][j] = fmaf(av_[i], bv_[j], acc[i][j]);
    }
    __syncthreads();
  }
#pragma unroll
  for (int i = 0; i < 4; ++i) {
    int row = m0 + (tm << 2) + i;
    if (row < M)
      *(float4*)&C[(size_t)row * D_DIM + n0 + (tn << 2)] =
          make_float4(acc[i][0], acc[i][1], acc[i][2], acc[i][3]);
  }
}

// ---------------- SpMM (CSR) + tanh (+ optional fused row l2-normalize) ----------------
// One 128-thread block per row; each thread owns 4 consecutive floats (float4).

template <int NORM>
__global__ __launch_bounds__(128) void k_spmm_tanh(const float* __restrict__ T, const int* __restrict__ rp,
                                                   const int* __restrict__ scol, const float* __restrict__ sval,
                                                   float* __restrict__ out) {
  const int r = blockIdx.x;
  const int t = threadIdx.x;
  const float4* Tv = (const float4*)T;
  float4 acc = make_float4(0.f, 0.f, 0.f, 0.f);
  const int beg = rp[r], end = rp[r + 1];
  for (int e = beg; e < end; ++e) {
    const int c = scol[e];
    const float v = sval[e];
    float4 x = Tv[(size_t)c * 128 + t];
    acc.x = fmaf(v, x.x, acc.x);
    acc.y = fmaf(v, x.y, acc.y);
    acc.z = fmaf(v, x.z, acc.z);
    acc.w = fmaf(v, x.w, acc.w);
  }
  acc.x = tanhf(acc.x);
  acc.y = tanhf(acc.y);
  acc.z = tanhf(acc.z);
  acc.w = tanhf(acc.w);
  if (NORM) {
    float ss = acc.x * acc.x + acc.y * acc.y + acc.z * acc.z + acc.w * acc.w;
#pragma unroll
    for (int off = 1; off < 64; off <<= 1) ss += __shfl_xor(ss, off);
    __shared__ float wsum[2];
    if ((t & 63) == 0) wsum[t >> 6] = ss;
    __syncthreads();
    float tot = wsum[0] + wsum[1];
    float sc = rsqrtf(fmaxf(tot, 1e-12f));
    acc.x *= sc; acc.y *= sc; acc.z *= sc; acc.w *= sc;
  }
  ((float4*)out)[(size_t)r * 128 + t] = acc;
}

// ---------------- launch ----------------

extern "C" void kernel_launch(void* const* d_in, const int* in_sizes, int n_in,
                              void* d_out, int out_size, void* d_ws, size_t ws_size,
                              hipStream_t stream) {
  const float* X = (const float*)d_in[0];
  const int* erow = (const int*)d_in[1];
  const int* ecol = (const int*)d_in[2];
  const float* evalv = (const float*)d_in[3];
  const float* W1 = (const float*)d_in[4];
  const float* W2 = (const float*)d_in[5];
  const int N = in_sizes[0] / D_DIM;
  const int E = in_sizes[1];
  (void)n_in; (void)out_size; (void)ws_size;

  // workspace layout (~231 MB): T tile + CSR arrays
  char* w = (char*)d_ws;
  size_t off = 0;
  auto alloc = [&](size_t bytes) {
    void* p = w + off;
    off = (off + bytes + 255) & ~(size_t)255;
    return p;
  };
  float* T = (float*)alloc((size_t)N * D_DIM * 4);
  int* scol = (int*)alloc((size_t)E * 4);
  float* sval = (float*)alloc((size_t)E * 4);
  int* rowptr = (int*)alloc((size_t)(N + 1) * 4);
  int* cursor = (int*)alloc((size_t)N * 4);

  float* H = (float*)d_out;  // layer-1 hidden state lives in d_out (overwritten by layer-2 output)

  // CSR build (deterministic work each call; intra-row order is atomic-ordered,
  // only perturbs fp summation order within tolerance)
  hipMemsetAsync(cursor, 0, (size_t)N * 4, stream);
  k_hist<<<dim3((E + 255) / 256), dim3(256), 0, stream>>>(erow, cursor, E);
  k_scan<<<dim3(1), dim3(1024), 0, stream>>>(cursor, rowptr, N);
  hipMemcpyAsync(cursor, rowptr, (size_t)N * 4, hipMemcpyDeviceToDevice, stream);
  k_scatter<<<dim3((E + 255) / 256), dim3(256), 0, stream>>>(erow, ecol, evalv, cursor, scol, sval, E);

  dim3 ggrid((N + 63) / 64, 8);
  // layer 1
  k_gemm512<<<ggrid, dim3(256), 0, stream>>>(X, W1, T, N);
  k_spmm_tanh<0><<<dim3(N), dim3(128), 0, stream>>>(T, rowptr, scol, sval, H);
  // layer 2 (+ fused l2 normalize)
  k_gemm512<<<ggrid, dim3(256), 0, stream>>>(H, W2, T, N);
  k_spmm_tanh<1><<<dim3(N), dim3(128), 0, stream>>>(T, rowptr, scol, sval, (float*)d_out);
}

// Round 4
// 1944.354 us; speedup vs baseline: 1.9323x; 1.9323x over previous
//
#include <hip/hip_runtime.h>
#include <hip/hip_fp16.h>

#define D_DIM 512

typedef __attribute__((ext_vector_type(8))) short short8;
typedef __attribute__((ext_vector_type(4))) float f32x4;

__device__ inline float bf2f(unsigned short h) {
  return __builtin_bit_cast(float, (unsigned)h << 16);
}
__device__ inline unsigned short f2bf(float f) {
  unsigned u = __builtin_bit_cast(unsigned, f);
  u = u + 0x7FFFu + ((u >> 16) & 1u);  // RNE
  return (unsigned short)(u >> 16);
}

// ---------------- CSR build ----------------

__global__ __launch_bounds__(256) void k_hist(const int* __restrict__ row, int* __restrict__ cnt, int E) {
  int i = blockIdx.x * blockDim.x + threadIdx.x;
  if (i < E) atomicAdd(&cnt[row[i]], 1);
}

__global__ __launch_bounds__(1024) void k_scanA(const int* __restrict__ cnt, int* __restrict__ rp,
                                                int* __restrict__ bsum, int n) {
  __shared__ int s[1024];
  int i = blockIdx.x * 1024 + threadIdx.x;
  int v = (i < n) ? cnt[i] : 0;
  s[threadIdx.x] = v;
  __syncthreads();
  for (int off = 1; off < 1024; off <<= 1) {
    int t = (threadIdx.x >= off) ? s[threadIdx.x - off] : 0;
    __syncthreads();
    s[threadIdx.x] += t;
    __syncthreads();
  }
  if (i < n) rp[i] = s[threadIdx.x] - v;  // exclusive within block
  if (threadIdx.x == 1023) bsum[blockIdx.x] = s[1023];
}

__global__ __launch_bounds__(1024) void k_scanB(int* __restrict__ bsum, int nb) {
  __shared__ int s[1024];
  int v = (threadIdx.x < nb) ? bsum[threadIdx.x] : 0;
  s[threadIdx.x] = v;
  __syncthreads();
  for (int off = 1; off < 1024; off <<= 1) {
    int t = (threadIdx.x >= off) ? s[threadIdx.x - off] : 0;
    __syncthreads();
    s[threadIdx.x] += t;
    __syncthreads();
  }
  if (threadIdx.x < nb) bsum[threadIdx.x] = s[threadIdx.x] - v;  // exclusive
}

__global__ __launch_bounds__(256) void k_scanC(int* __restrict__ rp, const int* __restrict__ bsum, int n, int E) {
  int i = blockIdx.x * 256 + threadIdx.x;
  if (i < n) rp[i] += bsum[i >> 10];
  if (i == 0) rp[n] = E;
}

__global__ __launch_bounds__(256) void k_scatter(const int* __restrict__ row, const int* __restrict__ col,
                                                 const float* __restrict__ val, int* __restrict__ cur,
                                                 int* __restrict__ scol, float* __restrict__ sval, int E) {
  int i = blockIdx.x * blockDim.x + threadIdx.x;
  if (i < E) {
    int r = row[i];
    int p = atomicAdd(&cur[r], 1);
    scol[p] = col[i];
    sval[p] = val[i];
  }
}

// ---------------- f32 -> bf16 hi/lo split of A (X), with zero pad rows ----------------

__global__ __launch_bounds__(256) void k_convA(const float* __restrict__ X, unsigned short* __restrict__ Xh,
                                               unsigned short* __restrict__ Xl, long nValid4, long nTot4) {
  long i = (long)blockIdx.x * 256 + threadIdx.x;  // unit: 4 elements
  long stride = (long)gridDim.x * 256;
  for (; i < nTot4; i += stride) {
    float4 x = make_float4(0.f, 0.f, 0.f, 0.f);
    if (i < nValid4) x = ((const float4*)X)[i];
    float xs[4] = {x.x, x.y, x.z, x.w};
    unsigned h[4], l[4];
#pragma unroll
    for (int q = 0; q < 4; ++q) {
      h[q] = f2bf(xs[q]);
      l[q] = f2bf(xs[q] - bf2f((unsigned short)h[q]));
    }
    uint2 vh, vl;
    vh.x = h[0] | (h[1] << 16); vh.y = h[2] | (h[3] << 16);
    vl.x = l[0] | (l[1] << 16); vl.y = l[2] | (l[3] << 16);
    ((uint2*)Xh)[i] = vh;
    ((uint2*)Xl)[i] = vl;
  }
}

// ---------------- W repack: f32 [512][512] -> bf16 hi/lo fragment-major [k/8][n][8] ----------------

__global__ __launch_bounds__(256) void k_repackW(const float* __restrict__ W, unsigned short* __restrict__ Wh,
                                                 unsigned short* __restrict__ Wl) {
  int n = blockIdx.x * 256 + threadIdx.x;  // 0..511 (grid.x = 2)
  int kg = blockIdx.y;                      // 0..63
  short8 vh, vl;
#pragma unroll
  for (int j = 0; j < 8; ++j) {
    float w = W[(kg * 8 + j) * D_DIM + n];
    unsigned short hh = f2bf(w);
    unsigned short ll = f2bf(w - bf2f(hh));
    vh[j] = (short)hh;
    vl[j] = (short)ll;
  }
  *(short8*)(Wh + ((long)kg * D_DIM + n) * 8) = vh;
  *(short8*)(Wl + ((long)kg * D_DIM + n) * 8) = vl;
}

// ---------------- split-bf16 MFMA GEMM: C[Mp,512](fp16) = A(hi/lo) @ B(hi/lo) ----------------
// No LDS. 128x128 block tile, 4 waves (2x2), each wave 64x64 = 4x4 fragments of 16x16.
// A fragments: 16B contiguous global loads. B: fragment-major repacked, one 16B load each.
// Output is FP16 (11-bit mantissa) so the SpMM gather table costs 2B/elem but
// rounds 8x finer than bf16.

__global__ __launch_bounds__(256) void k_gemm(const unsigned short* __restrict__ Ah,
                                              const unsigned short* __restrict__ Al,
                                              const unsigned short* __restrict__ Bh,
                                              const unsigned short* __restrict__ Bl,
                                              unsigned short* __restrict__ Cout) {
  const int tid = threadIdx.x;
  const int lane = tid & 63;
  const int w = tid >> 6;
  const int wr = w >> 1, wc = w & 1;
  const int c = lane & 15, g = lane >> 4;
  const long r0 = (long)blockIdx.y * 128 + wr * 64;
  const int n0 = blockIdx.x * 128 + wc * 64;

  f32x4 acc[4][4] = {};

  const unsigned short* pAh = Ah + (r0 + c) * D_DIM + g * 8;
  const unsigned short* pAl = Al + (r0 + c) * D_DIM + g * 8;
  const unsigned short* pBh = Bh + ((long)g * D_DIM + n0 + c) * 8;
  const unsigned short* pBl = Bl + ((long)g * D_DIM + n0 + c) * 8;

#pragma unroll 4
  for (int k0 = 0; k0 < D_DIM; k0 += 32) {
    short8 ah[4], al[4], bh[4], bl[4];
#pragma unroll
    for (int m = 0; m < 4; ++m) {
      ah[m] = *(const short8*)(pAh + (long)m * 16 * D_DIM + k0);
      al[m] = *(const short8*)(pAl + (long)m * 16 * D_DIM + k0);
    }
#pragma unroll
    for (int nf = 0; nf < 4; ++nf) {
      long boff = ((long)(k0 >> 3) * D_DIM + nf * 16) * 8;
      bh[nf] = *(const short8*)(pBh + boff);
      bl[nf] = *(const short8*)(pBl + boff);
    }
#pragma unroll
    for (int m = 0; m < 4; ++m)
#pragma unroll
      for (int nf = 0; nf < 4; ++nf) {
        acc[m][nf] = __builtin_amdgcn_mfma_f32_16x16x32_bf16(ah[m], bh[nf], acc[m][nf], 0, 0, 0);
        acc[m][nf] = __builtin_amdgcn_mfma_f32_16x16x32_bf16(ah[m], bl[nf], acc[m][nf], 0, 0, 0);
        acc[m][nf] = __builtin_amdgcn_mfma_f32_16x16x32_bf16(al[m], bh[nf], acc[m][nf], 0, 0, 0);
      }
  }

  // D layout: row = 4*g + j, col = c  (within each 16x16 fragment)
#pragma unroll
  for (int m = 0; m < 4; ++m) {
    long row0 = r0 + m * 16 + g * 4;
#pragma unroll
    for (int nf = 0; nf < 4; ++nf)
#pragma unroll
      for (int j = 0; j < 4; ++j)
        Cout[(row0 + j) * D_DIM + n0 + nf * 16 + c] =
            __half_as_ushort(__float2half(acc[m][nf][j]));
  }
}

// ---------------- SpMM over fp16 table + tanh; MODE 0: emit bf16 hi/lo; MODE 1: l2-normalize, emit f32 ----------------
// One wave per row; lane owns 8 consecutive cols (one 16B gather per edge per lane).

template <int MODE>
__global__ __launch_bounds__(64) void k_spmm(const unsigned short* __restrict__ T, const int* __restrict__ rp,
                                             const int* __restrict__ scol, const float* __restrict__ sval,
                                             unsigned short* __restrict__ Hh, unsigned short* __restrict__ Hl,
                                             float* __restrict__ out) {
  const int r = blockIdx.x;
  const int t = threadIdx.x;
  float acc[8] = {};
  const int beg = rp[r], end = rp[r + 1];
  const uint4* Tv = (const uint4*)T;  // 8 fp16 per chunk, 64 chunks per row
  for (int e = beg; e < end; ++e) {
    const int ccol = scol[e];
    const float v = sval[e];
    uint4 x = Tv[(long)ccol * 64 + t];
    unsigned xs[4] = {x.x, x.y, x.z, x.w};
#pragma unroll
    for (int q = 0; q < 4; ++q) {
      float2 f = __half22float2(__builtin_bit_cast(__half2, xs[q]));
      acc[2 * q] = fmaf(v, f.x, acc[2 * q]);
      acc[2 * q + 1] = fmaf(v, f.y, acc[2 * q + 1]);
    }
  }
#pragma unroll
  for (int q = 0; q < 8; ++q) acc[q] = tanhf(acc[q]);
  if (MODE == 1) {
    float ss = 0.f;
#pragma unroll
    for (int q = 0; q < 8; ++q) ss = fmaf(acc[q], acc[q], ss);
#pragma unroll
    for (int off = 1; off < 64; off <<= 1) ss += __shfl_xor(ss, off);
    const float sc = rsqrtf(fmaxf(ss, 1e-12f));
    float4 o0 = make_float4(acc[0] * sc, acc[1] * sc, acc[2] * sc, acc[3] * sc);
    float4 o1 = make_float4(acc[4] * sc, acc[5] * sc, acc[6] * sc, acc[7] * sc);
    ((float4*)out)[(long)r * 128 + 2 * t] = o0;
    ((float4*)out)[(long)r * 128 + 2 * t + 1] = o1;
  } else {
    unsigned h[8], l[8];
#pragma unroll
    for (int q = 0; q < 8; ++q) {
      h[q] = f2bf(acc[q]);
      l[q] = f2bf(acc[q] - bf2f((unsigned short)h[q]));
    }
    uint4 vh, vl;
    vh.x = h[0] | (h[1] << 16); vh.y = h[2] | (h[3] << 16);
    vh.z = h[4] | (h[5] << 16); vh.w = h[6] | (h[7] << 16);
    vl.x = l[0] | (l[1] << 16); vl.y = l[2] | (l[3] << 16);
    vl.z = l[4] | (l[5] << 16); vl.w = l[6] | (l[7] << 16);
    ((uint4*)Hh)[(long)r * 64 + t] = vh;
    ((uint4*)Hl)[(long)r * 64 + t] = vl;
  }
}

// ---------------- launch ----------------

extern "C" void kernel_launch(void* const* d_in, const int* in_sizes, int n_in,
                              void* d_out, int out_size, void* d_ws, size_t ws_size,
                              hipStream_t stream) {
  const float* X = (const float*)d_in[0];
  const int* erow = (const int*)d_in[1];
  const int* ecol = (const int*)d_in[2];
  const float* evalv = (const float*)d_in[3];
  const float* W1 = (const float*)d_in[4];
  const float* W2 = (const float*)d_in[5];
  const int N = in_sizes[0] / D_DIM;
  const int E = in_sizes[1];
  (void)n_in; (void)out_size; (void)ws_size;

  const int MB = (N + 127) / 128;     // 782 m-panels
  const long Mp = (long)MB * 128;     // padded rows: 100096

  char* wsp = (char*)d_ws;
  size_t off = 0;
  auto alloc = [&](size_t bytes) {
    void* p = wsp + off;
    off = (off + bytes + 255) & ~(size_t)255;
    return p;
  };
  unsigned short* T    = (unsigned short*)alloc(Mp * D_DIM * 2);  // GEMM output (fp16 gather table)
  unsigned short* XlHh = (unsigned short*)alloc(Mp * D_DIM * 2);  // Xl for layer1, then Hh
  int* scol   = (int*)alloc((size_t)E * 4);
  float* sval = (float*)alloc((size_t)E * 4);
  int* rowptr = (int*)alloc((size_t)(N + 1) * 4);
  int* cursor = (int*)alloc((size_t)N * 4);
  int* bsum   = (int*)alloc(1024 * 4);
  unsigned short* W1h = (unsigned short*)alloc((size_t)D_DIM * D_DIM * 2);
  unsigned short* W1l = (unsigned short*)alloc((size_t)D_DIM * D_DIM * 2);
  unsigned short* W2h = (unsigned short*)alloc((size_t)D_DIM * D_DIM * 2);
  unsigned short* W2l = (unsigned short*)alloc((size_t)D_DIM * D_DIM * 2);

  unsigned short* XhHl = (unsigned short*)d_out;  // Xh for layer1, then Hl (dead before final output write)

  const int nScanBlk = (N + 1023) / 1024;

  // CSR build
  hipMemsetAsync(cursor, 0, (size_t)N * 4, stream);
  k_hist<<<dim3((E + 255) / 256), dim3(256), 0, stream>>>(erow, cursor, E);
  k_scanA<<<dim3(nScanBlk), dim3(1024), 0, stream>>>(cursor, rowptr, bsum, N);
  k_scanB<<<dim3(1), dim3(1024), 0, stream>>>(bsum, nScanBlk);
  k_scanC<<<dim3((N + 255) / 256), dim3(256), 0, stream>>>(rowptr, bsum, N, E);
  hipMemcpyAsync(cursor, rowptr, (size_t)N * 4, hipMemcpyDeviceToDevice, stream);
  k_scatter<<<dim3((E + 255) / 256), dim3(256), 0, stream>>>(erow, ecol, evalv, cursor, scol, sval, E);

  // operand prep
  k_convA<<<dim3(4096), dim3(256), 0, stream>>>(X, XhHl, XlHh, (long)N * D_DIM / 4, Mp * D_DIM / 4);
  k_repackW<<<dim3(2, 64), dim3(256), 0, stream>>>(W1, W1h, W1l);
  k_repackW<<<dim3(2, 64), dim3(256), 0, stream>>>(W2, W2h, W2l);

  // layer 1
  k_gemm<<<dim3(4, MB), dim3(256), 0, stream>>>(XhHl, XlHh, W1h, W1l, T);
  k_spmm<0><<<dim3(N), dim3(64), 0, stream>>>(T, rowptr, scol, sval, XlHh, XhHl, nullptr);
  // layer 2
  k_gemm<<<dim3(4, MB), dim3(256), 0, stream>>>(XlHh, XhHl, W2h, W2l, T);
  k_spmm<1><<<dim3(N), dim3(64), 0, stream>>>(T, rowptr, scol, sval, nullptr, nullptr, (float*)d_out);
}

// Round 5
// 1918.461 us; speedup vs baseline: 1.9584x; 1.0135x over previous
//
#include <hip/hip_runtime.h>
#include <hip/hip_fp16.h>

#define D_DIM 512

typedef __attribute__((ext_vector_type(8))) short short8;
typedef __attribute__((ext_vector_type(4))) float f32x4;
typedef __attribute__((ext_vector_type(4))) unsigned uint4v;
typedef __attribute__((ext_vector_type(2))) float float2v;

__device__ inline float bf2f(unsigned short h) {
  return __builtin_bit_cast(float, (unsigned)h << 16);
}
__device__ inline unsigned short f2bf(float f) {
  unsigned u = __builtin_bit_cast(unsigned, f);
  u = u + 0x7FFFu + ((u >> 16) & 1u);  // RNE
  return (unsigned short)(u >> 16);
}

// ---------------- CSR build ----------------

__global__ __launch_bounds__(256) void k_hist(const int* __restrict__ row, int* __restrict__ cnt, int E) {
  int i = blockIdx.x * blockDim.x + threadIdx.x;
  if (i < E) atomicAdd(&cnt[row[i]], 1);
}

__global__ __launch_bounds__(1024) void k_scanA(const int* __restrict__ cnt, int* __restrict__ rp,
                                                int* __restrict__ bsum, int n) {
  __shared__ int s[1024];
  int i = blockIdx.x * 1024 + threadIdx.x;
  int v = (i < n) ? cnt[i] : 0;
  s[threadIdx.x] = v;
  __syncthreads();
  for (int off = 1; off < 1024; off <<= 1) {
    int t = (threadIdx.x >= off) ? s[threadIdx.x - off] : 0;
    __syncthreads();
    s[threadIdx.x] += t;
    __syncthreads();
  }
  if (i < n) rp[i] = s[threadIdx.x] - v;  // exclusive within block
  if (threadIdx.x == 1023) bsum[blockIdx.x] = s[1023];
}

__global__ __launch_bounds__(1024) void k_scanB(int* __restrict__ bsum, int nb) {
  __shared__ int s[1024];
  int v = (threadIdx.x < nb) ? bsum[threadIdx.x] : 0;
  s[threadIdx.x] = v;
  __syncthreads();
  for (int off = 1; off < 1024; off <<= 1) {
    int t = (threadIdx.x >= off) ? s[threadIdx.x - off] : 0;
    __syncthreads();
    s[threadIdx.x] += t;
    __syncthreads();
  }
  if (threadIdx.x < nb) bsum[threadIdx.x] = s[threadIdx.x] - v;  // exclusive
}

__global__ __launch_bounds__(256) void k_scanC(int* __restrict__ rp, const int* __restrict__ bsum, int n, int E) {
  int i = blockIdx.x * 256 + threadIdx.x;
  if (i < n) rp[i] += bsum[i >> 10];
  if (i == 0) rp[n] = E;
}

__global__ __launch_bounds__(256) void k_scatter(const int* __restrict__ row, const int* __restrict__ col,
                                                 const float* __restrict__ val, int* __restrict__ cur,
                                                 int* __restrict__ scol, float* __restrict__ sval, int E) {
  int i = blockIdx.x * blockDim.x + threadIdx.x;
  if (i < E) {
    int r = row[i];
    int p = atomicAdd(&cur[r], 1);
    scol[p] = col[i];
    sval[p] = val[i];
  }
}

// ---------------- f32 -> bf16 hi/lo split of A (X), with zero pad rows ----------------

__global__ __launch_bounds__(256) void k_convA(const float* __restrict__ X, unsigned short* __restrict__ Xh,
                                               unsigned short* __restrict__ Xl, long nValid4, long nTot4) {
  long i = (long)blockIdx.x * 256 + threadIdx.x;  // unit: 4 elements
  long stride = (long)gridDim.x * 256;
  for (; i < nTot4; i += stride) {
    float4 x = make_float4(0.f, 0.f, 0.f, 0.f);
    if (i < nValid4) x = ((const float4*)X)[i];
    float xs[4] = {x.x, x.y, x.z, x.w};
    unsigned h[4], l[4];
#pragma unroll
    for (int q = 0; q < 4; ++q) {
      h[q] = f2bf(xs[q]);
      l[q] = f2bf(xs[q] - bf2f((unsigned short)h[q]));
    }
    uint2 vh, vl;
    vh.x = h[0] | (h[1] << 16); vh.y = h[2] | (h[3] << 16);
    vl.x = l[0] | (l[1] << 16); vl.y = l[2] | (l[3] << 16);
    ((uint2*)Xh)[i] = vh;
    ((uint2*)Xl)[i] = vl;
  }
}

// ---------------- W repack: f32 [512][512] -> bf16 hi/lo fragment-major [k/8][n][8] ----------------

__global__ __launch_bounds__(256) void k_repackW(const float* __restrict__ W, unsigned short* __restrict__ Wh,
                                                 unsigned short* __restrict__ Wl) {
  int n = blockIdx.x * 256 + threadIdx.x;  // 0..511 (grid.x = 2)
  int kg = blockIdx.y;                      // 0..63
  short8 vh, vl;
#pragma unroll
  for (int j = 0; j < 8; ++j) {
    float w = W[(kg * 8 + j) * D_DIM + n];
    unsigned short hh = f2bf(w);
    unsigned short ll = f2bf(w - bf2f(hh));
    vh[j] = (short)hh;
    vl[j] = (short)ll;
  }
  *(short8*)(Wh + ((long)kg * D_DIM + n) * 8) = vh;
  *(short8*)(Wl + ((long)kg * D_DIM + n) * 8) = vl;
}

// ---------------- split-bf16 MFMA GEMM: C[Mp,512](fp16) = A(hi/lo) @ B(hi/lo) ----------------
// No LDS. 128x128 block tile, 4 waves (2x2), each wave 64x64 = 4x4 fragments of 16x16.
// T writes stay CACHED (L2/L3) — the following SpMM gathers from T.

__global__ __launch_bounds__(256) void k_gemm(const unsigned short* __restrict__ Ah,
                                              const unsigned short* __restrict__ Al,
                                              const unsigned short* __restrict__ Bh,
                                              const unsigned short* __restrict__ Bl,
                                              unsigned short* __restrict__ Cout) {
  const int tid = threadIdx.x;
  const int lane = tid & 63;
  const int w = tid >> 6;
  const int wr = w >> 1, wc = w & 1;
  const int c = lane & 15, g = lane >> 4;
  const long r0 = (long)blockIdx.y * 128 + wr * 64;
  const int n0 = blockIdx.x * 128 + wc * 64;

  f32x4 acc[4][4] = {};

  const unsigned short* pAh = Ah + (r0 + c) * D_DIM + g * 8;
  const unsigned short* pAl = Al + (r0 + c) * D_DIM + g * 8;
  const unsigned short* pBh = Bh + ((long)g * D_DIM + n0 + c) * 8;
  const unsigned short* pBl = Bl + ((long)g * D_DIM + n0 + c) * 8;

#pragma unroll 4
  for (int k0 = 0; k0 < D_DIM; k0 += 32) {
    short8 ah[4], al[4], bh[4], bl[4];
#pragma unroll
    for (int m = 0; m < 4; ++m) {
      ah[m] = *(const short8*)(pAh + (long)m * 16 * D_DIM + k0);
      al[m] = *(const short8*)(pAl + (long)m * 16 * D_DIM + k0);
    }
#pragma unroll
    for (int nf = 0; nf < 4; ++nf) {
      long boff = ((long)(k0 >> 3) * D_DIM + nf * 16) * 8;
      bh[nf] = *(const short8*)(pBh + boff);
      bl[nf] = *(const short8*)(pBl + boff);
    }
#pragma unroll
    for (int m = 0; m < 4; ++m)
#pragma unroll
      for (int nf = 0; nf < 4; ++nf) {
        acc[m][nf] = __builtin_amdgcn_mfma_f32_16x16x32_bf16(ah[m], bh[nf], acc[m][nf], 0, 0, 0);
        acc[m][nf] = __builtin_amdgcn_mfma_f32_16x16x32_bf16(ah[m], bl[nf], acc[m][nf], 0, 0, 0);
        acc[m][nf] = __builtin_amdgcn_mfma_f32_16x16x32_bf16(al[m], bh[nf], acc[m][nf], 0, 0, 0);
      }
  }

  // D layout: row = 4*g + j, col = c  (within each 16x16 fragment)
#pragma unroll
  for (int m = 0; m < 4; ++m) {
    long row0 = r0 + m * 16 + g * 4;
#pragma unroll
    for (int nf = 0; nf < 4; ++nf)
#pragma unroll
      for (int j = 0; j < 4; ++j)
        Cout[(row0 + j) * D_DIM + n0 + nf * 16 + c] =
            __half_as_ushort(__float2half(acc[m][nf][j]));
  }
}

// ---------------- SpMM over fp16 table + tanh ----------------
// 4 waves per row (256 threads); edges split contiguously across waves; each
// lane owns 8 consecutive cols (one 16B gather per edge). Partials combined
// through 8KB LDS. All OUTPUT stores are non-temporal so the 102MB gather
// table stays Infinity-Cache-resident (round-4: write streams evicted it,
// pushing 1.8GB/dispatch to HBM).
// MODE 0: emit bf16 hi/lo pair for the next GEMM. MODE 1: l2-normalize, f32.

template <int MODE>
__global__ __launch_bounds__(256) void k_spmm(const unsigned short* __restrict__ T, const int* __restrict__ rp,
                                              const int* __restrict__ scol, const float* __restrict__ sval,
                                              unsigned short* __restrict__ Hh, unsigned short* __restrict__ Hl,
                                              float* __restrict__ out) {
  __shared__ float p[4][D_DIM];
  __shared__ float wss[4];
  const int r = blockIdx.x;
  const int tid = threadIdx.x;
  const int w = tid >> 6, lane = tid & 63;
  const int beg = rp[r], end = rp[r + 1];
  const int cnt = end - beg;
  const int eb = beg + ((cnt * w) >> 2);
  const int ee = beg + ((cnt * (w + 1)) >> 2);

  float acc[8] = {};
  const uint4* Tv = (const uint4*)T;  // 8 fp16 per chunk, 64 chunks per row
  for (int e = eb; e < ee; ++e) {
    const int ccol = scol[e];
    const float v = sval[e];
    uint4 x = Tv[(long)ccol * 64 + lane];
    unsigned xs[4] = {x.x, x.y, x.z, x.w};
#pragma unroll
    for (int q = 0; q < 4; ++q) {
      float2 f = __half22float2(__builtin_bit_cast(__half2, xs[q]));
      acc[2 * q] = fmaf(v, f.x, acc[2 * q]);
      acc[2 * q + 1] = fmaf(v, f.y, acc[2 * q + 1]);
    }
  }
  *(float4*)&p[w][lane * 8] = make_float4(acc[0], acc[1], acc[2], acc[3]);
  *(float4*)&p[w][lane * 8 + 4] = make_float4(acc[4], acc[5], acc[6], acc[7]);
  __syncthreads();

  const int c = tid * 2;  // each thread finalizes 2 columns
  float s0 = p[0][c] + p[1][c] + p[2][c] + p[3][c];
  float s1 = p[0][c + 1] + p[1][c + 1] + p[2][c + 1] + p[3][c + 1];
  s0 = tanhf(s0);
  s1 = tanhf(s1);

  if (MODE == 0) {
    unsigned h0 = f2bf(s0), h1 = f2bf(s1);
    unsigned l0 = f2bf(s0 - bf2f((unsigned short)h0));
    unsigned l1 = f2bf(s1 - bf2f((unsigned short)h1));
    __builtin_nontemporal_store(h0 | (h1 << 16), (unsigned*)Hh + (long)r * 256 + tid);
    __builtin_nontemporal_store(l0 | (l1 << 16), (unsigned*)Hl + (long)r * 256 + tid);
  } else {
    float ss = fmaf(s0, s0, s1 * s1);
#pragma unroll
    for (int off = 1; off < 64; off <<= 1) ss += __shfl_xor(ss, off);
    if (lane == 0) wss[w] = ss;
    __syncthreads();
    const float tot = wss[0] + wss[1] + wss[2] + wss[3];
    const float sc = rsqrtf(fmaxf(tot, 1e-12f));
    float2v o;
    o.x = s0 * sc;
    o.y = s1 * sc;
    __builtin_nontemporal_store(o, (float2v*)out + (long)r * 256 + tid);
  }
}

// ---------------- launch ----------------

extern "C" void kernel_launch(void* const* d_in, const int* in_sizes, int n_in,
                              void* d_out, int out_size, void* d_ws, size_t ws_size,
                              hipStream_t stream) {
  const float* X = (const float*)d_in[0];
  const int* erow = (const int*)d_in[1];
  const int* ecol = (const int*)d_in[2];
  const float* evalv = (const float*)d_in[3];
  const float* W1 = (const float*)d_in[4];
  const float* W2 = (const float*)d_in[5];
  const int N = in_sizes[0] / D_DIM;
  const int E = in_sizes[1];
  (void)n_in; (void)out_size; (void)ws_size;

  const int MB = (N + 127) / 128;     // 782 m-panels
  const long Mp = (long)MB * 128;     // padded rows: 100096

  char* wsp = (char*)d_ws;
  size_t off = 0;
  auto alloc = [&](size_t bytes) {
    void* p = wsp + off;
    off = (off + bytes + 255) & ~(size_t)255;
    return p;
  };
  unsigned short* T    = (unsigned short*)alloc(Mp * D_DIM * 2);  // GEMM output (fp16 gather table)
  unsigned short* XlHh = (unsigned short*)alloc(Mp * D_DIM * 2);  // Xl for layer1, then Hh
  int* scol   = (int*)alloc((size_t)E * 4);
  float* sval = (float*)alloc((size_t)E * 4);
  int* rowptr = (int*)alloc((size_t)(N + 1) * 4);
  int* cursor = (int*)alloc((size_t)N * 4);
  int* bsum   = (int*)alloc(1024 * 4);
  unsigned short* W1h = (unsigned short*)alloc((size_t)D_DIM * D_DIM * 2);
  unsigned short* W1l = (unsigned short*)alloc((size_t)D_DIM * D_DIM * 2);
  unsigned short* W2h = (unsigned short*)alloc((size_t)D_DIM * D_DIM * 2);
  unsigned short* W2l = (unsigned short*)alloc((size_t)D_DIM * D_DIM * 2);

  unsigned short* XhHl = (unsigned short*)d_out;  // Xh for layer1, then Hl (dead before final output write)

  const int nScanBlk = (N + 1023) / 1024;

  // CSR build
  hipMemsetAsync(cursor, 0, (size_t)N * 4, stream);
  k_hist<<<dim3((E + 255) / 256), dim3(256), 0, stream>>>(erow, cursor, E);
  k_scanA<<<dim3(nScanBlk), dim3(1024), 0, stream>>>(cursor, rowptr, bsum, N);
  k_scanB<<<dim3(1), dim3(1024), 0, stream>>>(bsum, nScanBlk);
  k_scanC<<<dim3((N + 255) / 256), dim3(256), 0, stream>>>(rowptr, bsum, N, E);
  hipMemcpyAsync(cursor, rowptr, (size_t)N * 4, hipMemcpyDeviceToDevice, stream);
  k_scatter<<<dim3((E + 255) / 256), dim3(256), 0, stream>>>(erow, ecol, evalv, cursor, scol, sval, E);

  // operand prep
  k_convA<<<dim3(4096), dim3(256), 0, stream>>>(X, XhHl, XlHh, (long)N * D_DIM / 4, Mp * D_DIM / 4);
  k_repackW<<<dim3(2, 64), dim3(256), 0, stream>>>(W1, W1h, W1l);
  k_repackW<<<dim3(2, 64), dim3(256), 0, stream>>>(W2, W2h, W2l);

  // layer 1
  k_gemm<<<dim3(4, MB), dim3(256), 0, stream>>>(XhHl, XlHh, W1h, W1l, T);
  k_spmm<0><<<dim3(N), dim3(256), 0, stream>>>(T, rowptr, scol, sval, XlHh, XhHl, nullptr);
  // layer 2
  k_gemm<<<dim3(4, MB), dim3(256), 0, stream>>>(XlHh, XhHl, W2h, W2l, T);
  k_spmm<1><<<dim3(N), dim3(256), 0, stream>>>(T, rowptr, scol, sval, nullptr, nullptr, (float*)d_out);
}

// Round 7
// 1596.847 us; speedup vs baseline: 2.3528x; 1.2014x over previous
//
#include <hip/hip_runtime.h>
#include <hip/hip_fp16.h>

#define D_DIM 512

typedef __attribute__((ext_vector_type(8))) _Float16 half8;
typedef __attribute__((ext_vector_type(4))) float f32x4;
typedef __attribute__((ext_vector_type(2))) float float2v;

__device__ inline unsigned short f16b(float f) {
  return __half_as_ushort(__float2half(f));
}

// ---------------- CSR build ----------------

__global__ __launch_bounds__(256) void k_hist(const int* __restrict__ row, int* __restrict__ cnt, int E) {
  int i = blockIdx.x * blockDim.x + threadIdx.x;
  if (i < E) atomicAdd(&cnt[row[i]], 1);
}

__global__ __launch_bounds__(1024) void k_scanA(const int* __restrict__ cnt, int* __restrict__ rp,
                                                int* __restrict__ bsum, int n) {
  __shared__ int s[1024];
  int i = blockIdx.x * 1024 + threadIdx.x;
  int v = (i < n) ? cnt[i] : 0;
  s[threadIdx.x] = v;
  __syncthreads();
  for (int off = 1; off < 1024; off <<= 1) {
    int t = (threadIdx.x >= off) ? s[threadIdx.x - off] : 0;
    __syncthreads();
    s[threadIdx.x] += t;
    __syncthreads();
  }
  if (i < n) rp[i] = s[threadIdx.x] - v;  // exclusive within block
  if (threadIdx.x == 1023) bsum[blockIdx.x] = s[1023];
}

__global__ __launch_bounds__(1024) void k_scanB(int* __restrict__ bsum, int nb) {
  __shared__ int s[1024];
  int v = (threadIdx.x < nb) ? bsum[threadIdx.x] : 0;
  s[threadIdx.x] = v;
  __syncthreads();
  for (int off = 1; off < 1024; off <<= 1) {
    int t = (threadIdx.x >= off) ? s[threadIdx.x - off] : 0;
    __syncthreads();
    s[threadIdx.x] += t;
    __syncthreads();
  }
  if (threadIdx.x < nb) bsum[threadIdx.x] = s[threadIdx.x] - v;  // exclusive
}

__global__ __launch_bounds__(256) void k_scanC(int* __restrict__ rp, const int* __restrict__ bsum, int n, int E) {
  int i = blockIdx.x * 256 + threadIdx.x;
  if (i < n) rp[i] += bsum[i >> 10];
  if (i == 0) rp[n] = E;
}

__global__ __launch_bounds__(256) void k_scatter(const int* __restrict__ row, const int* __restrict__ col,
                                                 const float* __restrict__ val, int* __restrict__ cur,
                                                 int* __restrict__ scol, float* __restrict__ sval, int E) {
  int i = blockIdx.x * blockDim.x + threadIdx.x;
  if (i < E) {
    int r = row[i];
    int p = atomicAdd(&cur[r], 1);
    scol[p] = col[i];
    sval[p] = val[i];
  }
}

// ---------------- f32 -> f16 convert of X, with zero pad rows ----------------

__global__ __launch_bounds__(256) void k_convA(const float* __restrict__ X, unsigned short* __restrict__ Xf,
                                               long nValid4, long nTot4) {
  long i = (long)blockIdx.x * 256 + threadIdx.x;  // unit: 4 elements
  long stride = (long)gridDim.x * 256;
  for (; i < nTot4; i += stride) {
    float4 x = make_float4(0.f, 0.f, 0.f, 0.f);
    if (i < nValid4) x = ((const float4*)X)[i];
    uint2 v;
    v.x = (unsigned)f16b(x.x) | ((unsigned)f16b(x.y) << 16);
    v.y = (unsigned)f16b(x.z) | ((unsigned)f16b(x.w) << 16);
    ((uint2*)Xf)[i] = v;
  }
}

// ---------------- W repack: f32 [512][512] -> f16 fragment-major [k/8][n][8] ----------------

__global__ __launch_bounds__(256) void k_repackW(const float* __restrict__ W, _Float16* __restrict__ Wf) {
  int n = blockIdx.x * 256 + threadIdx.x;  // 0..511 (grid.x = 2)
  int kg = blockIdx.y;                      // 0..63
  half8 v;
#pragma unroll
  for (int j = 0; j < 8; ++j) v[j] = (_Float16)W[(kg * 8 + j) * D_DIM + n];
  *(half8*)(Wf + ((long)kg * D_DIM + n) * 8) = v;
}

// ---------------- f16 MFMA GEMM: C[Mp,512](f16) = A(f16) @ B(f16) ----------------
// No LDS. 128x128 block tile, 4 waves (2x2), each wave 64x64 = 4x4 fragments of 16x16.
// 1-D grid with XCD decode: the 4 n-blocks of one A row-panel run on the SAME
// XCD back-to-back, so the A panel is fetched ~once per L2 instead of 4x.

__global__ __launch_bounds__(256) void k_gemm(const _Float16* __restrict__ A,
                                              const _Float16* __restrict__ B,
                                              _Float16* __restrict__ Cout, int MB) {
  const int id = blockIdx.x;
  const int xcd = id & 7;
  const int s = id >> 3;
  const int panel = (s >> 2) * 8 + xcd;
  if (panel >= MB) return;
  const int nb = s & 3;

  const int tid = threadIdx.x;
  const int lane = tid & 63;
  const int w = tid >> 6;
  const int wr = w >> 1, wc = w & 1;
  const int c = lane & 15, g = lane >> 4;
  const long r0 = (long)panel * 128 + wr * 64;
  const int n0 = nb * 128 + wc * 64;

  f32x4 acc[4][4] = {};

  const _Float16* pA = A + (r0 + c) * D_DIM + g * 8;
  const _Float16* pB = B + ((long)g * D_DIM + n0 + c) * 8;

#pragma unroll 4
  for (int k0 = 0; k0 < D_DIM; k0 += 32) {
    half8 a[4], b[4];
#pragma unroll
    for (int m = 0; m < 4; ++m) a[m] = *(const half8*)(pA + (long)m * 16 * D_DIM + k0);
#pragma unroll
    for (int nf = 0; nf < 4; ++nf)
      b[nf] = *(const half8*)(pB + ((long)(k0 >> 3) * D_DIM + nf * 16) * 8);
#pragma unroll
    for (int m = 0; m < 4; ++m)
#pragma unroll
      for (int nf = 0; nf < 4; ++nf)
        acc[m][nf] = __builtin_amdgcn_mfma_f32_16x16x32_f16(a[m], b[nf], acc[m][nf], 0, 0, 0);
  }

  // D layout: row = 4*g + j, col = c  (within each 16x16 fragment)
#pragma unroll
  for (int m = 0; m < 4; ++m) {
    long row0 = r0 + m * 16 + g * 4;
#pragma unroll
    for (int nf = 0; nf < 4; ++nf)
#pragma unroll
      for (int j = 0; j < 4; ++j)
        Cout[(row0 + j) * D_DIM + n0 + nf * 16 + c] = (_Float16)acc[m][nf][j];
  }
}

// ---------------- SpMM over f16 table + tanh ----------------
// 4 waves per row (256 threads); edges split contiguously across waves; each
// lane gathers 16B (8 f16 cols) per edge. Partials combined through 8KB LDS.
// MODE 0: emit f16 H for the next GEMM. MODE 1: l2-normalize, emit f32.

template <int MODE>
__global__ __launch_bounds__(256) void k_spmm(const unsigned short* __restrict__ T, const int* __restrict__ rp,
                                              const int* __restrict__ scol, const float* __restrict__ sval,
                                              unsigned* __restrict__ Hf, float* __restrict__ out) {
  __shared__ float p[4][D_DIM];
  __shared__ float wss[4];
  const int r = blockIdx.x;
  const int tid = threadIdx.x;
  const int w = tid >> 6, lane = tid & 63;
  const int beg = rp[r], end = rp[r + 1];
  const int cnt = end - beg;
  const int eb = beg + ((cnt * w) >> 2);
  const int ee = beg + ((cnt * (w + 1)) >> 2);

  float acc[8] = {};
  const uint4* Tv = (const uint4*)T;  // 8 f16 per chunk, 64 chunks per row
  for (int e = eb; e < ee; ++e) {
    const int ccol = scol[e];
    const float v = sval[e];
    uint4 x = Tv[(long)ccol * 64 + lane];
    unsigned xs[4] = {x.x, x.y, x.z, x.w};
#pragma unroll
    for (int q = 0; q < 4; ++q) {
      float2 f = __half22float2(__builtin_bit_cast(__half2, xs[q]));
      acc[2 * q] = fmaf(v, f.x, acc[2 * q]);
      acc[2 * q + 1] = fmaf(v, f.y, acc[2 * q + 1]);
    }
  }
  *(float4*)&p[w][lane * 8] = make_float4(acc[0], acc[1], acc[2], acc[3]);
  *(float4*)&p[w][lane * 8 + 4] = make_float4(acc[4], acc[5], acc[6], acc[7]);
  __syncthreads();

  const int c = tid * 2;  // each thread finalizes 2 columns
  float s0 = p[0][c] + p[1][c] + p[2][c] + p[3][c];
  float s1 = p[0][c + 1] + p[1][c + 1] + p[2][c + 1] + p[3][c + 1];
  s0 = tanhf(s0);
  s1 = tanhf(s1);

  if (MODE == 0) {
    unsigned hv = (unsigned)f16b(s0) | ((unsigned)f16b(s1) << 16);
    __builtin_nontemporal_store(hv, Hf + (long)r * 256 + tid);
  } else {
    float ss = fmaf(s0, s0, s1 * s1);
#pragma unroll
    for (int off = 1; off < 64; off <<= 1) ss += __shfl_xor(ss, off);
    if (lane == 0) wss[w] = ss;
    __syncthreads();
    const float tot = wss[0] + wss[1] + wss[2] + wss[3];
    const float sc = rsqrtf(fmaxf(tot, 1e-12f));
    float2v o;
    o.x = s0 * sc;
    o.y = s1 * sc;
    __builtin_nontemporal_store(o, (float2v*)out + (long)r * 256 + tid);
  }
}

// ---------------- launch ----------------

extern "C" void kernel_launch(void* const* d_in, const int* in_sizes, int n_in,
                              void* d_out, int out_size, void* d_ws, size_t ws_size,
                              hipStream_t stream) {
  const float* X = (const float*)d_in[0];
  const int* erow = (const int*)d_in[1];
  const int* ecol = (const int*)d_in[2];
  const float* evalv = (const float*)d_in[3];
  const float* W1 = (const float*)d_in[4];
  const float* W2 = (const float*)d_in[5];
  const int N = in_sizes[0] / D_DIM;
  const int E = in_sizes[1];
  (void)n_in; (void)out_size; (void)ws_size;

  const int MB = (N + 127) / 128;     // 782 m-panels
  const long Mp = (long)MB * 128;     // padded rows: 100096

  char* wsp = (char*)d_ws;
  size_t off = 0;
  auto alloc = [&](size_t bytes) {
    void* p = wsp + off;
    off = (off + bytes + 255) & ~(size_t)255;
    return p;
  };
  unsigned short* T  = (unsigned short*)alloc(Mp * D_DIM * 2);  // GEMM output (f16 gather table)
  unsigned short* Af = (unsigned short*)alloc(Mp * D_DIM * 2);  // X-f16 for layer 1, then H-f16
  int* scol   = (int*)alloc((size_t)E * 4);
  float* sval = (float*)alloc((size_t)E * 4);
  int* rowptr = (int*)alloc((size_t)(N + 1) * 4);
  int* cursor = (int*)alloc((size_t)N * 4);
  int* bsum   = (int*)alloc(1024 * 4);
  _Float16* W1f = (_Float16*)alloc((size_t)D_DIM * D_DIM * 2);
  _Float16* W2f = (_Float16*)alloc((size_t)D_DIM * D_DIM * 2);

  const int nScanBlk = (N + 1023) / 1024;
  const int gemmGrid = 32 * ((MB + 7) / 8);  // 8 xcd * 4 n-blocks * ceil(MB/8)

  // CSR build
  hipMemsetAsync(cursor, 0, (size_t)N * 4, stream);
  k_hist<<<dim3((E + 255) / 256), dim3(256), 0, stream>>>(erow, cursor, E);
  k_scanA<<<dim3(nScanBlk), dim3(1024), 0, stream>>>(cursor, rowptr, bsum, N);
  k_scanB<<<dim3(1), dim3(1024), 0, stream>>>(bsum, nScanBlk);
  k_scanC<<<dim3((N + 255) / 256), dim3(256), 0, stream>>>(rowptr, bsum, N, E);
  hipMemcpyAsync(cursor, rowptr, (size_t)N * 4, hipMemcpyDeviceToDevice, stream);
  k_scatter<<<dim3((E + 255) / 256), dim3(256), 0, stream>>>(erow, ecol, evalv, cursor, scol, sval, E);

  // operand prep
  k_convA<<<dim3(4096), dim3(256), 0, stream>>>(X, Af, (long)N * D_DIM / 4, Mp * D_DIM / 4);
  k_repackW<<<dim3(2, 64), dim3(256), 0, stream>>>(W1, W1f);
  k_repackW<<<dim3(2, 64), dim3(256), 0, stream>>>(W2, W2f);

  // layer 1
  k_gemm<<<dim3(gemmGrid), dim3(256), 0, stream>>>((const _Float16*)Af, W1f, (_Float16*)T, MB);
  k_spmm<0><<<dim3(N), dim3(256), 0, stream>>>(T, rowptr, scol, sval, (unsigned*)Af, nullptr);
  // layer 2
  k_gemm<<<dim3(gemmGrid), dim3(256), 0, stream>>>((const _Float16*)Af, W2f, (_Float16*)T, MB);
  k_spmm<1><<<dim3(N), dim3(256), 0, stream>>>(T, rowptr, scol, sval, nullptr, (float*)d_out);
}

// Round 9
// 1554.227 us; speedup vs baseline: 2.4173x; 1.0274x over previous
//
#include <hip/hip_runtime.h>
#include <hip/hip_fp16.h>

#define D_DIM 512

typedef __attribute__((ext_vector_type(8))) _Float16 half8;
typedef __attribute__((ext_vector_type(4))) float f32x4;
typedef __attribute__((ext_vector_type(2))) float float2v;

__device__ inline unsigned short f16b(float f) {
  return __half_as_ushort(__float2half(f));
}

// ---------------- CSR build ----------------

__global__ __launch_bounds__(256) void k_hist(const int* __restrict__ row, int* __restrict__ cnt, int E) {
  int i = blockIdx.x * blockDim.x + threadIdx.x;
  if (i < E) atomicAdd(&cnt[row[i]], 1);
}

__global__ __launch_bounds__(1024) void k_scanA(const int* __restrict__ cnt, int* __restrict__ rp,
                                                int* __restrict__ bsum, int n) {
  __shared__ int s[1024];
  int i = blockIdx.x * 1024 + threadIdx.x;
  int v = (i < n) ? cnt[i] : 0;
  s[threadIdx.x] = v;
  __syncthreads();
  for (int off = 1; off < 1024; off <<= 1) {
    int t = (threadIdx.x >= off) ? s[threadIdx.x - off] : 0;
    __syncthreads();
    s[threadIdx.x] += t;
    __syncthreads();
  }
  if (i < n) rp[i] = s[threadIdx.x] - v;  // exclusive within block
  if (threadIdx.x == 1023) bsum[blockIdx.x] = s[1023];
}

__global__ __launch_bounds__(1024) void k_scanB(int* __restrict__ bsum, int nb) {
  __shared__ int s[1024];
  int v = (threadIdx.x < nb) ? bsum[threadIdx.x] : 0;
  s[threadIdx.x] = v;
  __syncthreads();
  for (int off = 1; off < 1024; off <<= 1) {
    int t = (threadIdx.x >= off) ? s[threadIdx.x - off] : 0;
    __syncthreads();
    s[threadIdx.x] += t;
    __syncthreads();
  }
  if (threadIdx.x < nb) bsum[threadIdx.x] = s[threadIdx.x] - v;  // exclusive
}

__global__ __launch_bounds__(256) void k_scanC(int* __restrict__ rp, const int* __restrict__ bsum, int n, int E) {
  int i = blockIdx.x * 256 + threadIdx.x;
  if (i < n) rp[i] += bsum[i >> 10];
  if (i == 0) rp[n] = E;
}

__global__ __launch_bounds__(256) void k_scatter(const int* __restrict__ row, const int* __restrict__ col,
                                                 const float* __restrict__ val, int* __restrict__ cur,
                                                 int2* __restrict__ edat, int E) {
  int i = blockIdx.x * blockDim.x + threadIdx.x;
  if (i < E) {
    int r = row[i];
    int p = atomicAdd(&cur[r], 1);
    edat[p] = make_int2(col[i], __float_as_int(val[i]));
  }
}

// ---------------- f32 -> f16 convert of X, with zero pad rows ----------------

__global__ __launch_bounds__(256) void k_convA(const float* __restrict__ X, unsigned short* __restrict__ Xf,
                                               long nValid4, long nTot4) {
  long i = (long)blockIdx.x * 256 + threadIdx.x;  // unit: 4 elements
  long stride = (long)gridDim.x * 256;
  for (; i < nTot4; i += stride) {
    float4 x = make_float4(0.f, 0.f, 0.f, 0.f);
    if (i < nValid4) x = ((const float4*)X)[i];
    uint2 v;
    v.x = (unsigned)f16b(x.x) | ((unsigned)f16b(x.y) << 16);
    v.y = (unsigned)f16b(x.z) | ((unsigned)f16b(x.w) << 16);
    ((uint2*)Xf)[i] = v;
  }
}

// ---------------- W repack: f32 [512][512] -> f16 fragment-major [k/8][n][8] ----------------

__global__ __launch_bounds__(256) void k_repackW(const float* __restrict__ W, _Float16* __restrict__ Wf) {
  int n = blockIdx.x * 256 + threadIdx.x;  // 0..511 (grid.x = 2)
  int kg = blockIdx.y;                      // 0..63
  half8 v;
#pragma unroll
  for (int j = 0; j < 8; ++j) v[j] = (_Float16)W[(kg * 8 + j) * D_DIM + n];
  *(half8*)(Wf + ((long)kg * D_DIM + n) * 8) = v;
}

// ---------------- f16 MFMA GEMM: C[Mp,512](f16) = A(f16) @ B(f16) ----------------
// No-LDS main loop. 128x128 block tile, 4 waves (2x2), each wave 64x64 = 4x4
// fragments of 16x16. XCD-decoded 1-D grid (4 n-blocks of one A panel on the
// same XCD). Epilogue transposes each wave's 64x64 acc through a private LDS
// region so C is written as coalesced 16B f16 stores (round-7: 2B scattered
// stores were the suspected GEMM bottleneck).

__global__ __launch_bounds__(256) void k_gemm(const _Float16* __restrict__ A,
                                              const _Float16* __restrict__ B,
                                              _Float16* __restrict__ Cout, int MB) {
  const int id = blockIdx.x;
  const int xcd = id & 7;
  const int s = id >> 3;
  const int panel = (s >> 2) * 8 + xcd;
  if (panel >= MB) return;
  const int nb = s & 3;

  const int tid = threadIdx.x;
  const int lane = tid & 63;
  const int w = tid >> 6;
  const int wr = w >> 1, wc = w & 1;
  const int c = lane & 15, g = lane >> 4;
  const long r0 = (long)panel * 128 + wr * 64;
  const int n0 = nb * 128 + wc * 64;

  f32x4 acc[4][4] = {};

  const _Float16* pA = A + (r0 + c) * D_DIM + g * 8;
  const _Float16* pB = B + ((long)g * D_DIM + n0 + c) * 8;

#pragma unroll 4
  for (int k0 = 0; k0 < D_DIM; k0 += 32) {
    half8 a[4], b[4];
#pragma unroll
    for (int m = 0; m < 4; ++m) a[m] = *(const half8*)(pA + (long)m * 16 * D_DIM + k0);
#pragma unroll
    for (int nf = 0; nf < 4; ++nf)
      b[nf] = *(const half8*)(pB + ((long)(k0 >> 3) * D_DIM + nf * 16) * 8);
#pragma unroll
    for (int m = 0; m < 4; ++m)
#pragma unroll
      for (int nf = 0; nf < 4; ++nf)
        acc[m][nf] = __builtin_amdgcn_mfma_f32_16x16x32_f16(a[m], b[nf], acc[m][nf], 0, 0, 0);
  }

  // Epilogue: per m-slice (16 rows x 64 cols), scatter acc (D layout:
  // row=4g+j, col=c per fragment) into this wave's LDS region, then reload
  // row-major and emit two 16B f16 stores per lane.
  __shared__ float ep[4][16][68];  // 68-f32 stride: 16B-aligned rows, conflict-spread
#pragma unroll
  for (int m = 0; m < 4; ++m) {
#pragma unroll
    for (int nf = 0; nf < 4; ++nf)
#pragma unroll
      for (int j = 0; j < 4; ++j)
        ep[w][g * 4 + j][nf * 16 + c] = acc[m][nf][j];
    __syncthreads();
    {
      const int row = lane >> 2;  // 0..15
      const int ch = lane & 3;    // 16-col chunk
      float v[16];
#pragma unroll
      for (int q = 0; q < 16; ++q) v[q] = ep[w][row][ch * 16 + q];
      half8 h0, h1;
#pragma unroll
      for (int q = 0; q < 8; ++q) {
        h0[q] = (_Float16)v[q];
        h1[q] = (_Float16)v[8 + q];
      }
      _Float16* dst = Cout + (r0 + m * 16 + row) * D_DIM + n0 + ch * 16;
      *(half8*)dst = h0;
      *(half8*)(dst + 8) = h1;
    }
    __syncthreads();
  }
}

// ---------------- SpMM over f16 table + tanh ----------------
// 4 waves per row (256 threads); edges split contiguously across waves; each
// lane gathers 16B (8 f16 cols) per edge. Partials combined through 8KB LDS.
// MODE 0: emit f16 H for the next GEMM. MODE 1: l2-normalize, emit f32.

template <int MODE>
__global__ __launch_bounds__(256) void k_spmm(const unsigned short* __restrict__ T, const int* __restrict__ rp,
                                              const int2* __restrict__ edat,
                                              unsigned* __restrict__ Hf, float* __restrict__ out) {
  __shared__ float p[4][D_DIM];
  __shared__ float wss[4];
  const int r = blockIdx.x;
  const int tid = threadIdx.x;
  const int w = tid >> 6, lane = tid & 63;
  const int beg = rp[r], end = rp[r + 1];
  const int cnt = end - beg;
  const int eb = beg + ((cnt * w) >> 2);
  const int ee = beg + ((cnt * (w + 1)) >> 2);

  float acc[8] = {};
  const uint4* Tv = (const uint4*)T;  // 8 f16 per chunk, 64 chunks per row
  for (int e = eb; e < ee; ++e) {
    const int2 ed = edat[e];
    const int ccol = ed.x;
    const float v = __int_as_float(ed.y);
    uint4 x = Tv[(long)ccol * 64 + lane];
    unsigned xs[4] = {x.x, x.y, x.z, x.w};
#pragma unroll
    for (int q = 0; q < 4; ++q) {
      float2 f = __half22float2(__builtin_bit_cast(__half2, xs[q]));
      acc[2 * q] = fmaf(v, f.x, acc[2 * q]);
      acc[2 * q + 1] = fmaf(v, f.y, acc[2 * q + 1]);
    }
  }
  *(float4*)&p[w][lane * 8] = make_float4(acc[0], acc[1], acc[2], acc[3]);
  *(float4*)&p[w][lane * 8 + 4] = make_float4(acc[4], acc[5], acc[6], acc[7]);
  __syncthreads();

  const int c = tid * 2;  // each thread finalizes 2 columns
  float s0 = p[0][c] + p[1][c] + p[2][c] + p[3][c];
  float s1 = p[0][c + 1] + p[1][c + 1] + p[2][c + 1] + p[3][c + 1];
  s0 = tanhf(s0);
  s1 = tanhf(s1);

  if (MODE == 0) {
    unsigned hv = (unsigned)f16b(s0) | ((unsigned)f16b(s1) << 16);
    __builtin_nontemporal_store(hv, Hf + (long)r * 256 + tid);
  } else {
    float ss = fmaf(s0, s0, s1 * s1);
#pragma unroll
    for (int off = 1; off < 64; off <<= 1) ss += __shfl_xor(ss, off);
    if (lane == 0) wss[w] = ss;
    __syncthreads();
    const float tot = wss[0] + wss[1] + wss[2] + wss[3];
    const float sc = rsqrtf(fmaxf(tot, 1e-12f));
    float2v o;
    o.x = s0 * sc;
    o.y = s1 * sc;
    __builtin_nontemporal_store(o, (float2v*)out + (long)r * 256 + tid);
  }
}

// ---------------- launch ----------------

extern "C" void kernel_launch(void* const* d_in, const int* in_sizes, int n_in,
                              void* d_out, int out_size, void* d_ws, size_t ws_size,
                              hipStream_t stream) {
  const float* X = (const float*)d_in[0];
  const int* erow = (const int*)d_in[1];
  const int* ecol = (const int*)d_in[2];
  const float* evalv = (const float*)d_in[3];
  const float* W1 = (const float*)d_in[4];
  const float* W2 = (const float*)d_in[5];
  const int N = in_sizes[0] / D_DIM;
  const int E = in_sizes[1];
  (void)n_in; (void)out_size; (void)ws_size;

  const int MB = (N + 127) / 128;     // 782 m-panels
  const long Mp = (long)MB * 128;     // padded rows: 100096

  char* wsp = (char*)d_ws;
  size_t off = 0;
  auto alloc = [&](size_t bytes) {
    void* p = wsp + off;
    off = (off + bytes + 255) & ~(size_t)255;
    return p;
  };
  unsigned short* T  = (unsigned short*)alloc(Mp * D_DIM * 2);  // GEMM output (f16 gather table)
  unsigned short* Af = (unsigned short*)alloc(Mp * D_DIM * 2);  // X-f16 for layer 1, then H-f16
  int2* edat  = (int2*)alloc((size_t)E * 8);
  int* rowptr = (int*)alloc((size_t)(N + 1) * 4);
  int* cursor = (int*)alloc((size_t)N * 4);
  int* bsum   = (int*)alloc(1024 * 4);
  _Float16* W1f = (_Float16*)alloc((size_t)D_DIM * D_DIM * 2);
  _Float16* W2f = (_Float16*)alloc((size_t)D_DIM * D_DIM * 2);

  const int nScanBlk = (N + 1023) / 1024;
  const int gemmGrid = 32 * ((MB + 7) / 8);  // 8 xcd * 4 n-blocks * ceil(MB/8)

  // CSR build
  hipMemsetAsync(cursor, 0, (size_t)N * 4, stream);
  k_hist<<<dim3((E + 255) / 256), dim3(256), 0, stream>>>(erow, cursor, E);
  k_scanA<<<dim3(nScanBlk), dim3(1024), 0, stream>>>(cursor, rowptr, bsum, N);
  k_scanB<<<dim3(1), dim3(1024), 0, stream>>>(bsum, nScanBlk);
  k_scanC<<<dim3((N + 255) / 256), dim3(256), 0, stream>>>(rowptr, bsum, N, E);
  hipMemcpyAsync(cursor, rowptr, (size_t)N * 4, hipMemcpyDeviceToDevice, stream);
  k_scatter<<<dim3((E + 255) / 256), dim3(256), 0, stream>>>(erow, ecol, evalv, cursor, edat, E);

  // operand prep
  k_convA<<<dim3(4096), dim3(256), 0, stream>>>(X, Af, (long)N * D_DIM / 4, Mp * D_DIM / 4);
  k_repackW<<<dim3(2, 64), dim3(256), 0, stream>>>(W1, W1f);
  k_repackW<<<dim3(2, 64), dim3(256), 0, stream>>>(W2, W2f);

  // layer 1
  k_gemm<<<dim3(gemmGrid), dim3(256), 0, stream>>>((const _Float16*)Af, W1f, (_Float16*)T, MB);
  k_spmm<0><<<dim3(N), dim3(256), 0, stream>>>(T, rowptr, edat, (unsigned*)Af, nullptr);
  // layer 2
  k_gemm<<<dim3(gemmGrid), dim3(256), 0, stream>>>((const _Float16*)Af, W2f, (_Float16*)T, MB);
  k_spmm<1><<<dim3(N), dim3(256), 0, stream>>>(T, rowptr, edat, nullptr, (float*)d_out);
}